// Round 1
// baseline (2233.177 us; speedup 1.0000x reference)
//
#include <hip/hip_runtime.h>
#include <math.h>

#define N_NODES 100000
#define N_EDGES 3200000
#define HID 32
#define NEG 0.2f

// ---- monotone float <-> uint key for atomicMax over floats ----
__device__ __forceinline__ unsigned fkey(float f) {
    unsigned u = __float_as_uint(f);
    return (u & 0x80000000u) ? ~u : (u | 0x80000000u);
}
__device__ __forceinline__ float funkey(unsigned k) {
    if (k == 0u) return -INFINITY;
    unsigned u = (k & 0x80000000u) ? (k ^ 0x80000000u) : ~k;
    return __uint_as_float(u);
}

__device__ __forceinline__ float lrelu(float x) { return x > 0.f ? x : NEG * x; }

// ---------------- degree / loop_attr (shared by both layers) ----------------
__global__ void k_zero_deg(float* deg, float* loopsum) {
    int i = blockIdx.x * blockDim.x + threadIdx.x;
    if (i < N_NODES) {
        deg[i] = 0.f;
        loopsum[i * 4 + 0] = 0.f; loopsum[i * 4 + 1] = 0.f;
        loopsum[i * 4 + 2] = 0.f; loopsum[i * 4 + 3] = 0.f;
    }
}

__global__ void k_deg(const int* __restrict__ dst, const float4* __restrict__ ea,
                      float* deg, float* loopsum) {
    int stride = gridDim.x * blockDim.x;
    for (int e = blockIdx.x * blockDim.x + threadIdx.x; e < N_EDGES; e += stride) {
        int d = dst[e];
        float4 a = ea[e];
        atomicAdd(&deg[d], 1.0f);
        atomicAdd(&loopsum[d * 4 + 0], a.x);
        atomicAdd(&loopsum[d * 4 + 1], a.y);
        atomicAdd(&loopsum[d * 4 + 2], a.z);
        atomicAdd(&loopsum[d * 4 + 3], a.w);
    }
}

__global__ void k_loopattr(const float* __restrict__ deg, float* loopsum) {
    int i = blockIdx.x * blockDim.x + threadIdx.x;
    if (i >= N_NODES) return;
    float inv = 1.0f / fmaxf(deg[i], 1.0f);
    float4 s = ((float4*)loopsum)[i];
    s.x *= inv; s.y *= inv; s.z *= inv; s.w *= inv;
    ((float4*)loopsum)[i] = s;
}

// ---------------- per-layer node prep: xfeat = h@W, a_src/a_dst, init accum ----
template <int LAYER>
__global__ void k_node_prep(const float* __restrict__ xin,   // L1: x (N,5); L2: h (N,32)
                            const float* __restrict__ encW, const float* __restrict__ encb,
                            const float* __restrict__ W,
                            const float* __restrict__ att_src, const float* __restrict__ att_dst,
                            float* __restrict__ xfeat, float* __restrict__ a_src,
                            float* __restrict__ a_dst, float* __restrict__ denom,
                            unsigned* __restrict__ amaxkey, float* __restrict__ out_acc) {
    __shared__ float sW[HID * HID];
    __shared__ float sAs[HID], sAd[HID];
    __shared__ float sEW[5 * HID], sEb[HID];
    int tid = threadIdx.x;
    for (int j = tid; j < HID * HID; j += blockDim.x) sW[j] = W[j];
    if (tid < HID) { sAs[tid] = att_src[tid]; sAd[tid] = att_dst[tid]; }
    if (LAYER == 1) {
        for (int j = tid; j < 5 * HID; j += blockDim.x) sEW[j] = encW[j];
        if (tid < HID) sEb[tid] = encb[tid];
    }
    __syncthreads();
    int i = blockIdx.x * blockDim.x + tid;
    if (i >= N_NODES) return;

    float h[HID];
    if (LAYER == 1) {
        float xi[5];
#pragma unroll
        for (int j = 0; j < 5; j++) xi[j] = xin[i * 5 + j];
#pragma unroll
        for (int k = 0; k < HID; k++) {
            float v = sEb[k];
#pragma unroll
            for (int j = 0; j < 5; j++) v += xi[j] * sEW[j * HID + k];
            h[k] = fmaxf(v, 0.f);
        }
    } else {
#pragma unroll
        for (int k = 0; k < HID; k++) h[k] = xin[i * HID + k];
    }
    float as = 0.f, ad = 0.f;
#pragma unroll
    for (int f = 0; f < HID; f++) {
        float v = 0.f;
#pragma unroll
        for (int k = 0; k < HID; k++) v += h[k] * sW[k * HID + f];
        xfeat[i * HID + f] = v;
        out_acc[i * HID + f] = 0.f;
        as += v * sAs[f];
        ad += v * sAd[f];
    }
    a_src[i] = as;
    a_dst[i] = ad;
    denom[i] = 0.f;
    amaxkey[i] = 0u;
}

// ---------------- edge pass 1: alpha + running max ----------------
__global__ void k_edge_alpha(const int* __restrict__ src, const int* __restrict__ dst,
                             const float4* __restrict__ ea,
                             const float* __restrict__ We, const float* __restrict__ att_e,
                             const float* __restrict__ a_src, const float* __restrict__ a_dst,
                             float* __restrict__ alpha, unsigned* __restrict__ amaxkey) {
    __shared__ float wa[4];
    if (threadIdx.x < 4) {
        float v = 0.f;
        for (int k = 0; k < HID; k++) v += We[threadIdx.x * HID + k] * att_e[k];
        wa[threadIdx.x] = v;
    }
    __syncthreads();
    float w0 = wa[0], w1 = wa[1], w2 = wa[2], w3 = wa[3];
    int stride = gridDim.x * blockDim.x;
    for (int e = blockIdx.x * blockDim.x + threadIdx.x; e < N_EDGES; e += stride) {
        int s = src[e], d = dst[e];
        float4 a = ea[e];
        float al = a_src[s] + a_dst[d] + a.x * w0 + a.y * w1 + a.z * w2 + a.w * w3;
        al = lrelu(al);
        alpha[e] = al;
        atomicMax(&amaxkey[d], fkey(al));
    }
}

// ---------------- node pass: self-loop alpha + final amax ----------------
__global__ void k_node_loopalpha(const float* __restrict__ loopattr,
                                 const float* __restrict__ We, const float* __restrict__ att_e,
                                 const float* __restrict__ a_src, const float* __restrict__ a_dst,
                                 const unsigned* __restrict__ amaxkey,
                                 float* __restrict__ amax_f, float* __restrict__ alpha_loop) {
    __shared__ float wa[4];
    if (threadIdx.x < 4) {
        float v = 0.f;
        for (int k = 0; k < HID; k++) v += We[threadIdx.x * HID + k] * att_e[k];
        wa[threadIdx.x] = v;
    }
    __syncthreads();
    int i = blockIdx.x * blockDim.x + threadIdx.x;
    if (i >= N_NODES) return;
    float4 la = ((const float4*)loopattr)[i];
    float al = a_src[i] + a_dst[i] + la.x * wa[0] + la.y * wa[1] + la.z * wa[2] + la.w * wa[3];
    al = lrelu(al);
    alpha_loop[i] = al;
    amax_f[i] = fmaxf(funkey(amaxkey[i]), al);
}

// ---------------- edge pass 2: ex, denom, out_acc (half-wave per edge) -------
__global__ void k_edge_acc(const int* __restrict__ src, const int* __restrict__ dst,
                           const float* __restrict__ alpha, const float* __restrict__ amax_f,
                           const float* __restrict__ xfeat,
                           float* __restrict__ denom, float* __restrict__ out_acc) {
    int lane = threadIdx.x & 31;
    int grp = threadIdx.x >> 5;
    int gPerBlk = blockDim.x >> 5;
    int stride = gridDim.x * gPerBlk;
    for (int e = blockIdx.x * gPerBlk + grp; e < N_EDGES; e += stride) {
        int s = src[e], d = dst[e];
        float ex = __expf(alpha[e] - amax_f[d]);
        if (lane == 0) atomicAdd(&denom[d], ex);
        atomicAdd(&out_acc[d * HID + lane], ex * xfeat[s * HID + lane]);
    }
}

// ---------------- node finalize: h_out = acc/denom + bias (+relu) ----------
template <int RELU>
__global__ void k_node_final(const float* __restrict__ out_acc, const float* __restrict__ denom,
                             const float* __restrict__ alpha_loop, const float* __restrict__ amax_f,
                             const float* __restrict__ xfeat, const float* __restrict__ bias,
                             float* __restrict__ hout) {
    __shared__ float sb[HID];
    if (threadIdx.x < HID) sb[threadIdx.x] = bias[threadIdx.x];
    __syncthreads();
    int i = blockIdx.x * blockDim.x + threadIdx.x;
    if (i >= N_NODES) return;
    float exl = __expf(alpha_loop[i] - amax_f[i]);
    float inv = 1.0f / (denom[i] + exl);
#pragma unroll
    for (int f = 0; f < HID; f++) {
        float v = (out_acc[i * HID + f] + exl * xfeat[i * HID + f]) * inv + sb[f];
        if (RELU) v = fmaxf(v, 0.f);
        hout[i * HID + f] = v;
    }
}

// ---------------- decode + log_softmax ----------------
__global__ void k_decode(const float* __restrict__ h, const float* __restrict__ decW,
                         const float* __restrict__ decb, const int* __restrict__ nt_ptr,
                         float* __restrict__ out) {
    __shared__ float sW[HID * 4];
    __shared__ float sb[4];
    int tid = threadIdx.x;
    for (int j = tid; j < HID * 4; j += blockDim.x) sW[j] = decW[j];
    if (tid < 4) sb[tid] = decb[tid];
    __syncthreads();
    int i = blockIdx.x * blockDim.x + tid;
    int nt = *nt_ptr;
    if (i >= nt) return;
    float o0 = sb[0], o1 = sb[1], o2 = sb[2], o3 = sb[3];
#pragma unroll
    for (int k = 0; k < HID; k++) {
        float hv = h[i * HID + k];
        o0 += hv * sW[k * 4 + 0];
        o1 += hv * sW[k * 4 + 1];
        o2 += hv * sW[k * 4 + 2];
        o3 += hv * sW[k * 4 + 3];
    }
    float m = fmaxf(fmaxf(o0, o1), fmaxf(o2, o3));
    float sum = __expf(o0 - m) + __expf(o1 - m) + __expf(o2 - m) + __expf(o3 - m);
    float ls = m + logf(sum);
    float4 r;
    r.x = o0 - ls; r.y = o1 - ls; r.z = o2 - ls; r.w = o3 - ls;
    ((float4*)out)[i] = r;
}

extern "C" void kernel_launch(void* const* d_in, const int* in_sizes, int n_in,
                              void* d_out, int out_size, void* d_ws, size_t ws_size,
                              hipStream_t stream) {
    const float* x = (const float*)d_in[0];
    const int* ei = (const int*)d_in[1];
    const float* edge_attr = (const float*)d_in[2];
    const int* num_trucks = (const int*)d_in[3];
    const float* enc_W = (const float*)d_in[4];
    const float* enc_b = (const float*)d_in[5];
    const float* c1_W = (const float*)d_in[6];
    const float* c1_att_src = (const float*)d_in[7];
    const float* c1_att_dst = (const float*)d_in[8];
    const float* c1_We = (const float*)d_in[9];
    const float* c1_att_e = (const float*)d_in[10];
    const float* c1_b = (const float*)d_in[11];
    const float* c2_W = (const float*)d_in[12];
    const float* c2_att_src = (const float*)d_in[13];
    const float* c2_att_dst = (const float*)d_in[14];
    const float* c2_We = (const float*)d_in[15];
    const float* c2_att_e = (const float*)d_in[16];
    const float* c2_b = (const float*)d_in[17];
    const float* dec_W = (const float*)d_in[18];
    const float* dec_b = (const float*)d_in[19];

    const int* srcp = ei;
    const int* dstp = ei + N_EDGES;

    float* ws = (float*)d_ws;
    size_t off = 0;
    float* xfeat = ws + off; off += (size_t)N_NODES * HID;   // 3.2M
    float* hbuf  = ws + off; off += (size_t)N_NODES * HID;   // 3.2M
    float* alpha = ws + off; off += (size_t)N_EDGES;         // 3.2M
    float* oacc  = ws + off; off += (size_t)N_NODES * HID;   // 3.2M
    float* asrc  = ws + off; off += N_NODES;
    float* adst  = ws + off; off += N_NODES;
    float* denom = ws + off; off += N_NODES;
    unsigned* amaxkey = (unsigned*)(ws + off); off += N_NODES;
    float* amaxf = ws + off; off += N_NODES;
    float* aloop = ws + off; off += N_NODES;
    float* deg   = ws + off; off += N_NODES;
    float* loopsum = ws + off; off += (size_t)N_NODES * 4;

    const int NB = 256;
    const int gNode = (N_NODES + NB - 1) / NB;       // 391
    const int gEdge = 2048;                           // grid-stride scalar edge kernels
    const int gAcc = 16384;                           // grid-stride half-wave edge kernel

    // shared deg / loop_attr
    k_zero_deg<<<gNode, NB, 0, stream>>>(deg, loopsum);
    k_deg<<<gEdge, NB, 0, stream>>>(dstp, (const float4*)edge_attr, deg, loopsum);
    k_loopattr<<<gNode, NB, 0, stream>>>(deg, loopsum);

    // ---- layer 1 (encoder fused into node prep) ----
    k_node_prep<1><<<gNode, NB, 0, stream>>>(x, enc_W, enc_b, c1_W, c1_att_src, c1_att_dst,
                                             xfeat, asrc, adst, denom, amaxkey, oacc);
    k_edge_alpha<<<gEdge, NB, 0, stream>>>(srcp, dstp, (const float4*)edge_attr, c1_We,
                                           c1_att_e, asrc, adst, alpha, amaxkey);
    k_node_loopalpha<<<gNode, NB, 0, stream>>>(loopsum, c1_We, c1_att_e, asrc, adst,
                                               amaxkey, amaxf, aloop);
    k_edge_acc<<<gAcc, NB, 0, stream>>>(srcp, dstp, alpha, amaxf, xfeat, denom, oacc);
    k_node_final<1><<<gNode, NB, 0, stream>>>(oacc, denom, aloop, amaxf, xfeat, c1_b, hbuf);

    // ---- layer 2 ----
    k_node_prep<2><<<gNode, NB, 0, stream>>>(hbuf, enc_W, enc_b, c2_W, c2_att_src, c2_att_dst,
                                             xfeat, asrc, adst, denom, amaxkey, oacc);
    k_edge_alpha<<<gEdge, NB, 0, stream>>>(srcp, dstp, (const float4*)edge_attr, c2_We,
                                           c2_att_e, asrc, adst, alpha, amaxkey);
    k_node_loopalpha<<<gNode, NB, 0, stream>>>(loopsum, c2_We, c2_att_e, asrc, adst,
                                               amaxkey, amaxf, aloop);
    k_edge_acc<<<gAcc, NB, 0, stream>>>(srcp, dstp, alpha, amaxf, xfeat, denom, oacc);
    k_node_final<0><<<gNode, NB, 0, stream>>>(oacc, denom, aloop, amaxf, xfeat, c2_b, hbuf);

    // ---- decode ----
    k_decode<<<gNode, NB, 0, stream>>>(hbuf, dec_W, dec_b, num_trucks, (float*)d_out);
}

// Round 2
// 836.823 us; speedup vs baseline: 2.6686x; 2.6686x over previous
//
#include <hip/hip_runtime.h>
#include <math.h>

#define N_NODES 100000
#define N_EDGES 3200000
#define HID 32
#define NEG 0.2f
#define NBLK 391   // ceil(N_NODES/256)

__device__ __forceinline__ float lrelu(float x) { return x > 0.f ? x : NEG * x; }

// ---------------- CSR build ----------------
__global__ void k_zero_deg(int* deg) {
    int i = blockIdx.x * blockDim.x + threadIdx.x;
    if (i < N_NODES) deg[i] = 0;
}

__global__ void k_count(const int* __restrict__ dst, int* __restrict__ deg) {
    int stride = gridDim.x * blockDim.x;
    for (int e = blockIdx.x * blockDim.x + threadIdx.x; e < N_EDGES; e += stride)
        atomicAdd(&deg[dst[e]], 1);
}

__global__ void k_scan1(const int* __restrict__ deg, int* __restrict__ tmp, int* __restrict__ bsum) {
    __shared__ int sd[256];
    int i = blockIdx.x * 256 + threadIdx.x;
    sd[threadIdx.x] = (i < N_NODES) ? deg[i] : 0;
    __syncthreads();
    for (int off = 1; off < 256; off <<= 1) {
        int t = (threadIdx.x >= off) ? sd[threadIdx.x - off] : 0;
        __syncthreads();
        sd[threadIdx.x] += t;
        __syncthreads();
    }
    if (i < N_NODES) tmp[i] = sd[threadIdx.x];
    if (threadIdx.x == 255) bsum[blockIdx.x] = sd[255];
}

__global__ void k_scan2(int* bsum) {
    __shared__ int sd[512];
    int t = threadIdx.x;
    sd[t] = (t < NBLK) ? bsum[t] : 0;
    __syncthreads();
    for (int off = 1; off < 512; off <<= 1) {
        int v = (t >= off) ? sd[t - off] : 0;
        __syncthreads();
        sd[t] += v;
        __syncthreads();
    }
    if (t < NBLK) bsum[t] = sd[t];
}

__global__ void k_scan3(const int* __restrict__ deg, const int* __restrict__ tmp,
                        const int* __restrict__ bsum, int* __restrict__ row_ptr,
                        int* __restrict__ cursor) {
    int i = blockIdx.x * 256 + threadIdx.x;
    if (i >= N_NODES) return;
    int off = (blockIdx.x == 0) ? 0 : bsum[blockIdx.x - 1];
    int incl = tmp[i] + off;
    row_ptr[i + 1] = incl;
    cursor[i] = incl - deg[i];
    if (i == 0) row_ptr[0] = 0;
}

// fill CSR: one pos-atomic per edge; store src and BOTH layers' edge-attn dots
__global__ void k_fill(const int* __restrict__ src, const int* __restrict__ dst,
                       const float4* __restrict__ ea,
                       const float* __restrict__ We1, const float* __restrict__ atte1,
                       const float* __restrict__ We2, const float* __restrict__ atte2,
                       int* __restrict__ cursor, int* __restrict__ csr_src,
                       float2* __restrict__ csr_dot) {
    __shared__ float wa1[4], wa2[4];
    int t = threadIdx.x;
    if (t < 4) {
        float v = 0.f;
        for (int k = 0; k < HID; k++) v += We1[t * HID + k] * atte1[k];
        wa1[t] = v;
    } else if (t < 8) {
        int c = t - 4;
        float v = 0.f;
        for (int k = 0; k < HID; k++) v += We2[c * HID + k] * atte2[k];
        wa2[c] = v;
    }
    __syncthreads();
    float a10 = wa1[0], a11 = wa1[1], a12 = wa1[2], a13 = wa1[3];
    float a20 = wa2[0], a21 = wa2[1], a22 = wa2[2], a23 = wa2[3];
    int stride = gridDim.x * blockDim.x;
    for (int e = blockIdx.x * blockDim.x + threadIdx.x; e < N_EDGES; e += stride) {
        int d = dst[e];
        float4 a = ea[e];
        int pos = atomicAdd(&cursor[d], 1);
        csr_src[pos] = src[e];
        float2 dt;
        dt.x = a.x * a10 + a.y * a11 + a.z * a12 + a.w * a13;
        dt.y = a.x * a20 + a.y * a21 + a.z * a22 + a.w * a23;
        csr_dot[pos] = dt;
    }
}

// ---------------- per-layer node prep: xfeat = h@W, a_src/a_dst ----------------
template <int LAYER>
__global__ void k_node_prep(const float* __restrict__ xin,
                            const float* __restrict__ encW, const float* __restrict__ encb,
                            const float* __restrict__ W,
                            const float* __restrict__ att_src, const float* __restrict__ att_dst,
                            float* __restrict__ xfeat, float* __restrict__ a_src,
                            float* __restrict__ a_dst) {
    __shared__ float sW[HID * HID];
    __shared__ float sAs[HID], sAd[HID];
    __shared__ float sEW[5 * HID], sEb[HID];
    int tid = threadIdx.x;
    for (int j = tid; j < HID * HID; j += blockDim.x) sW[j] = W[j];
    if (tid < HID) { sAs[tid] = att_src[tid]; sAd[tid] = att_dst[tid]; }
    if (LAYER == 1) {
        for (int j = tid; j < 5 * HID; j += blockDim.x) sEW[j] = encW[j];
        if (tid < HID) sEb[tid] = encb[tid];
    }
    __syncthreads();
    int i = blockIdx.x * blockDim.x + tid;
    if (i >= N_NODES) return;

    float h[HID];
    if (LAYER == 1) {
        float xi[5];
#pragma unroll
        for (int j = 0; j < 5; j++) xi[j] = xin[i * 5 + j];
#pragma unroll
        for (int k = 0; k < HID; k++) {
            float v = sEb[k];
#pragma unroll
            for (int j = 0; j < 5; j++) v += xi[j] * sEW[j * HID + k];
            h[k] = fmaxf(v, 0.f);
        }
    } else {
#pragma unroll
        for (int k = 0; k < HID; k++) h[k] = xin[i * HID + k];
    }
    float as = 0.f, ad = 0.f;
#pragma unroll
    for (int f = 0; f < HID; f++) {
        float v = 0.f;
#pragma unroll
        for (int k = 0; k < HID; k++) v += h[k] * sW[k * HID + f];
        xfeat[i * HID + f] = v;
        as += v * sAs[f];
        ad += v * sAd[f];
    }
    a_src[i] = as;
    a_dst[i] = ad;
}

// ---------------- gather: half-wave per node, online softmax, zero atomics ----
template <int RELU, int DCOMP>
__global__ void k_gather(const int* __restrict__ row_ptr, const int* __restrict__ csr_src,
                         const float2* __restrict__ csr_dot,
                         const float* __restrict__ a_src, const float* __restrict__ a_dst,
                         const float* __restrict__ xfeat, const float* __restrict__ bias,
                         float* __restrict__ hout) {
    int lane = threadIdx.x & 31;
    int node = (blockIdx.x * blockDim.x + threadIdx.x) >> 5;
    if (node >= N_NODES) return;
    int beg = row_ptr[node], end = row_ptr[node + 1];
    float adsti = a_dst[node];
    float m = -INFINITY, den = 0.f, acc = 0.f, dotsum = 0.f;
    for (int e = beg; e < end; e++) {
        int s = csr_src[e];
        float2 dt = csr_dot[e];
        float dot = (DCOMP == 0) ? dt.x : dt.y;
        dotsum += dot;
        float al = lrelu(a_src[s] + adsti + dot);
        float xs = xfeat[s * HID + lane];
        if (al > m) {
            float r = __expf(m - al);   // exp(-inf)=0 handles first iter
            den *= r; acc *= r; m = al;
        }
        float ex = __expf(al - m);
        den += ex;
        acc += ex * xs;
    }
    // self loop (processed last; order within softmax is irrelevant)
    float degf = (float)(end - beg);
    float loopdot = dotsum / fmaxf(degf, 1.0f);
    float all = lrelu(a_src[node] + adsti + loopdot);
    float xs = xfeat[node * HID + lane];
    if (all > m) {
        float r = __expf(m - all);
        den *= r; acc *= r; m = all;
    }
    float ex = __expf(all - m);
    den += ex;
    acc += ex * xs;

    float v = acc / den + bias[lane];
    if (RELU) v = fmaxf(v, 0.f);
    hout[node * HID + lane] = v;
}

// ---------------- decode + log_softmax ----------------
__global__ void k_decode(const float* __restrict__ h, const float* __restrict__ decW,
                         const float* __restrict__ decb, const int* __restrict__ nt_ptr,
                         float* __restrict__ out) {
    __shared__ float sW[HID * 4];
    __shared__ float sb[4];
    int tid = threadIdx.x;
    for (int j = tid; j < HID * 4; j += blockDim.x) sW[j] = decW[j];
    if (tid < 4) sb[tid] = decb[tid];
    __syncthreads();
    int i = blockIdx.x * blockDim.x + tid;
    int nt = *nt_ptr;
    if (i >= nt) return;
    float o0 = sb[0], o1 = sb[1], o2 = sb[2], o3 = sb[3];
#pragma unroll
    for (int k = 0; k < HID; k++) {
        float hv = h[i * HID + k];
        o0 += hv * sW[k * 4 + 0];
        o1 += hv * sW[k * 4 + 1];
        o2 += hv * sW[k * 4 + 2];
        o3 += hv * sW[k * 4 + 3];
    }
    float m = fmaxf(fmaxf(o0, o1), fmaxf(o2, o3));
    float sum = __expf(o0 - m) + __expf(o1 - m) + __expf(o2 - m) + __expf(o3 - m);
    float ls = m + logf(sum);
    float4 r;
    r.x = o0 - ls; r.y = o1 - ls; r.z = o2 - ls; r.w = o3 - ls;
    ((float4*)out)[i] = r;
}

extern "C" void kernel_launch(void* const* d_in, const int* in_sizes, int n_in,
                              void* d_out, int out_size, void* d_ws, size_t ws_size,
                              hipStream_t stream) {
    const float* x = (const float*)d_in[0];
    const int* ei = (const int*)d_in[1];
    const float* edge_attr = (const float*)d_in[2];
    const int* num_trucks = (const int*)d_in[3];
    const float* enc_W = (const float*)d_in[4];
    const float* enc_b = (const float*)d_in[5];
    const float* c1_W = (const float*)d_in[6];
    const float* c1_att_src = (const float*)d_in[7];
    const float* c1_att_dst = (const float*)d_in[8];
    const float* c1_We = (const float*)d_in[9];
    const float* c1_att_e = (const float*)d_in[10];
    const float* c1_b = (const float*)d_in[11];
    const float* c2_W = (const float*)d_in[12];
    const float* c2_att_src = (const float*)d_in[13];
    const float* c2_att_dst = (const float*)d_in[14];
    const float* c2_We = (const float*)d_in[15];
    const float* c2_att_e = (const float*)d_in[16];
    const float* c2_b = (const float*)d_in[17];
    const float* dec_W = (const float*)d_in[18];
    const float* dec_b = (const float*)d_in[19];

    const int* srcp = ei;
    const int* dstp = ei + N_EDGES;

    // workspace layout (all sizes multiples of 16B)
    char* wsb = (char*)d_ws;
    size_t off = 0;
    float2* csr_dot = (float2*)(wsb + off); off += (size_t)N_EDGES * 8;      // 25.6 MB
    int* csr_src    = (int*)(wsb + off);    off += (size_t)N_EDGES * 4;      // 12.8 MB
    float* xfeat    = (float*)(wsb + off);  off += (size_t)N_NODES * HID * 4; // 12.8 MB
    float* hbuf     = (float*)(wsb + off);  off += (size_t)N_NODES * HID * 4; // 12.8 MB
    int* row_ptr    = (int*)(wsb + off);    off += (size_t)(N_NODES + 4) * 4;
    int* cursor     = (int*)(wsb + off);    off += (size_t)N_NODES * 4;
    int* deg        = (int*)(wsb + off);    off += (size_t)N_NODES * 4;
    int* tmpscan    = (int*)(wsb + off);    off += (size_t)N_NODES * 4;
    int* bsum       = (int*)(wsb + off);    off += 512 * 4;
    float* asrc     = (float*)(wsb + off);  off += (size_t)N_NODES * 4;
    float* adst     = (float*)(wsb + off);  off += (size_t)N_NODES * 4;

    const int NB = 256;
    const int gNode = NBLK;                      // 391
    const int gEdge = 2048;                      // grid-stride edge kernels
    const int gGath = (N_NODES * 32 + NB - 1) / NB; // 12500

    // CSR build
    k_zero_deg<<<gNode, NB, 0, stream>>>(deg);
    k_count<<<gEdge, NB, 0, stream>>>(dstp, deg);
    k_scan1<<<gNode, NB, 0, stream>>>(deg, tmpscan, bsum);
    k_scan2<<<1, 512, 0, stream>>>(bsum);
    k_scan3<<<gNode, NB, 0, stream>>>(deg, tmpscan, bsum, row_ptr, cursor);
    k_fill<<<gEdge, NB, 0, stream>>>(srcp, dstp, (const float4*)edge_attr,
                                     c1_We, c1_att_e, c2_We, c2_att_e,
                                     cursor, csr_src, csr_dot);

    // layer 1 (encoder fused)
    k_node_prep<1><<<gNode, NB, 0, stream>>>(x, enc_W, enc_b, c1_W, c1_att_src, c1_att_dst,
                                             xfeat, asrc, adst);
    k_gather<1, 0><<<gGath, NB, 0, stream>>>(row_ptr, csr_src, csr_dot, asrc, adst,
                                             xfeat, c1_b, hbuf);

    // layer 2
    k_node_prep<2><<<gNode, NB, 0, stream>>>(hbuf, enc_W, enc_b, c2_W, c2_att_src, c2_att_dst,
                                             xfeat, asrc, adst);
    k_gather<0, 1><<<gGath, NB, 0, stream>>>(row_ptr, csr_src, csr_dot, asrc, adst,
                                             xfeat, c2_b, hbuf);

    // decode
    k_decode<<<gNode, NB, 0, stream>>>(hbuf, dec_W, dec_b, num_trucks, (float*)d_out);
}